// Round 3
// baseline (533.193 us; speedup 1.0000x reference)
//
#include <hip/hip_runtime.h>

#define ROWS 128
#define NUM_BASIS 67                        // GRID_SIZE + K = 64 + 3
#define TILE_FLOATS (ROWS * NUM_BASIS)      // 8576 floats = 34304 B (128B-multiple)
#define TILE_V4 (TILE_FLOATS / 4)           // 2144
#define NBLOCKS 1024                        // 4 resident blocks/CU * 256 CUs
#define NTHREADS 256

// Interior knots: knots[i] = (i-35)/32 for i in [3,67]; clamped outside.
// EXACT in float32 -> comparisons reproduce the reference's indicator semantics.
__device__ __forceinline__ float kv(int i) {
    i = min(max(i, 3), 67);
    return (float)(i - 35) * 0.03125f;
}

// Raw barrier with LDS-only wait. Unlike __syncthreads(), this does NOT drain
// vmcnt(0) -- global stores from the previous tile stay in flight across the
// barrier (T4 principle: never drain vmem in the main loop). LDS correctness:
// lgkmcnt(0) retires this thread's ds ops before the barrier; memory-clobber
// asm on both sides stops compiler reordering of LDS ops across it.
__device__ __forceinline__ void lgkm_barrier() {
    asm volatile("s_waitcnt lgkmcnt(0)" ::: "memory");
    __builtin_amdgcn_s_barrier();
    asm volatile("" ::: "memory");
}

__global__ __launch_bounds__(NTHREADS) void SplineBasis_kernel(const float* __restrict__ x,
                                                               float* __restrict__ out,
                                                               int B) {
    __shared__ __align__(16) float tile[TILE_FLOATS];
    const int tid = threadIdx.x;

    // Contiguous chunk of tiles per block (sequential HBM pages for x and out).
    const int ntiles = (B + ROWS - 1) / ROWS;       // 15625 for B = 2e6 (exact: 15625*128 = 2e6)
    const int q = ntiles / NBLOCKS, r = ntiles % NBLOCKS;
    const int bid = (int)blockIdx.x;
    const int myn = q + (bid < r ? 1 : 0);          // 15 or 16 tiles
    const int t0 = bid * q + min(bid, r);
    if (myn == 0) return;                           // uniform per block

    // One-time full zero of the LDS tile (per-tile re-zero below is 16 B/row).
    float4* t4 = (float4*)tile;
    for (int i = tid; i < TILE_V4; i += NTHREADS) t4[i] = make_float4(0.f, 0.f, 0.f, 0.f);

    // Preload x for the first tile (latency hides under the zero fill;
    // compiler inserts a counted vmcnt wait only at first use).
    float xv = 0.0f;
    bool havex = false;
    if (tid < ROWS) {
        const int row = t0 * ROWS + tid;
        if (row < B) { xv = x[row]; havex = true; }
    }

    int prev_c0 = -1;   // my previously scattered cells (my row only -> race-free)

    for (int t = 0; t < myn; ++t) {
        const int tile_idx = t0 + t;

        // (a) previous store phase's ds_reads are retired in all threads
        //     (each thread's reads complete before its last store issues;
        //      lgkmcnt(0) + barrier makes that global across the block).
        lgkm_barrier();

        if (tid < ROWS) {
            // Prefetch next tile's x FIRST: issued before this tile's stores,
            // so next iteration's wait is vmcnt(N) with N = stores in flight.
            float xnext = 0.0f;
            bool havenext = false;
            if (t + 1 < myn) {
                const int row = (tile_idx + 1) * ROWS + tid;
                if (row < B) { xnext = x[row]; havenext = true; }
            }

            // Re-zero exactly the 4 cells I wrote last tile (16 B vs 17 KB).
            if (prev_c0 >= 0) {
                tile[prev_c0 + 0] = 0.f; tile[prev_c0 + 1] = 0.f;
                tile[prev_c0 + 2] = 0.f; tile[prev_c0 + 3] = 0.f;
                prev_c0 = -1;
            }

            // Reference gives an all-zero row for x < -1, x >= 1, or NaN.
            if (havex && xv >= -1.0f && xv < 1.0f) {
                // Containing interval: knots[m] <= x < knots[m+1], m in [3,66].
                int cell = (int)floorf((xv + 1.0f) * 32.0f);
                cell = min(max(cell, 0), 63);
                int m = cell + 3;
                // Fix-up against exact knot values (rounding at boundaries).
                while (m > 3 && xv < kv(m)) --m;
                while (m < 66 && xv >= kv(m + 1)) ++m;

                // de Boor triangle: after degree-3 loop, N[j] = B_{m-3+j,3}(x).
                // Identical values to the reference's bottom-up DP.
                float N[4], left[4], right[4];
                N[0] = 1.0f;
#pragma unroll
                for (int d = 1; d <= 3; ++d) {
                    left[d]  = xv - kv(m + 1 - d);
                    right[d] = kv(m + d) - xv;
                    float saved = 0.0f;
#pragma unroll
                    for (int rr = 0; rr < d; ++rr) {
                        float temp = N[rr] / (right[rr + 1] + left[d - rr]);
                        N[rr] = saved + right[rr + 1] * temp;
                        saved = left[d - rr] * temp;
                    }
                    N[d] = saved;
                }

                const int c0 = tid * NUM_BASIS + (m - 3);   // m-3 in [0,63]
                tile[c0 + 0] = N[0];
                tile[c0 + 1] = N[1];
                tile[c0 + 2] = N[2];
                tile[c0 + 3] = N[3];
                prev_c0 = c0;
            }
            xv = xnext; havex = havenext;
        }

        // (b) scatter visible to all threads; stores below read LDS.
        lgkm_barrier();

        // Stream the tile to global: coalesced float4 stores, base byte offset
        // tile_idx*34304 (16B-aligned, 128B-line multiple). No vmem drain after:
        // these stores remain outstanding through the next tile's barriers.
        const int rows = min(ROWS, B - tile_idx * ROWS);
        if (rows == ROWS) {
            float4* o4 = (float4*)(out + (size_t)tile_idx * TILE_FLOATS);
            for (int i = tid; i < TILE_V4; i += NTHREADS) o4[i] = t4[i];
        } else if (rows > 0) {
            // Generic tail (not hit for B = 2,000,000).
            const int n = rows * NUM_BASIS;
            float* o = out + (size_t)tile_idx * TILE_FLOATS;
            for (int i = tid; i < n; i += NTHREADS) o[i] = tile[i];
        }
    }
}

extern "C" void kernel_launch(void* const* d_in, const int* in_sizes, int n_in,
                              void* d_out, int out_size, void* d_ws, size_t ws_size,
                              hipStream_t stream) {
    const float* x = (const float*)d_in[0];
    float* out = (float*)d_out;
    const int B = in_sizes[0];
    const int ntiles = (B + ROWS - 1) / ROWS;
    const int nblocks = ntiles < NBLOCKS ? ntiles : NBLOCKS;
    SplineBasis_kernel<<<nblocks, NTHREADS, 0, stream>>>(x, out, B);
}